// Round 3
// baseline (111.671 us; speedup 1.0000x reference)
//
#include <hip/hip_runtime.h>
#include <hip/hip_bf16.h>

// NT-Xent loss, MI355X, round 3.
//  k_prep     : fused fp32 row-norms + bf16 normalize + exact positives
//  k_flash    : sim = zn@zn^T via MFMA bf16, fixed-max LSE (logits<=2),
//               double-buffered async staging, ONE barrier per tile,
//               hoisted swizzled LDS addressing, XCD-swizzled grid
//  k_finalize : single block, direct scalar write (no memset node)

#define B_ 4096
#define N_ 8192
#define D_ 256
#define EPS_ 1e-8f
#define SPLITS 16
#define BM 128              // rows per block (4 waves x 32 rows)
#define BN 32               // cols per LDS tile
#define KC 8                // D/32 k-chunks
#define CPS (N_ / SPLITS)   // 512 cols per split
#define NT_ (CPS / BN)      // 16 tiles per split
#define LOG2E 1.44269504088896340736f

typedef __attribute__((ext_vector_type(8))) short bfrag_t;   // 8 bf16
typedef __attribute__((ext_vector_type(4))) float f32x4_t;   // MFMA C/D

__device__ __forceinline__ ushort f2bf_rne(float x) {
  union { float f; unsigned u; } a; a.f = x;
  unsigned r = a.u + 0x7FFFu + ((a.u >> 16) & 1u);
  return (ushort)(r >> 16);
}

__device__ __forceinline__ void cp16_lds(const uint4* g, uint4* l) {
  __builtin_amdgcn_global_load_lds(
      (const __attribute__((address_space(1))) unsigned int*)g,
      (__attribute__((address_space(3))) unsigned int*)l, 16, 0, 0);
}

// ---------------- fused normalize + positives: one wave per pair ----------------
__global__ __launch_bounds__(256) void k_prep(
    const float* __restrict__ zi, const float* __restrict__ zj,
    ushort* __restrict__ zn, float* __restrict__ pos) {
  const int w = threadIdx.x >> 6, lane = threadIdx.x & 63;
  const int p = blockIdx.x * 4 + w;
  float4 a = reinterpret_cast<const float4*>(zi + (size_t)p * D_)[lane];
  float4 b = reinterpret_cast<const float4*>(zj + (size_t)p * D_)[lane];
  float si = a.x * a.x + a.y * a.y + a.z * a.z + a.w * a.w;
  float sj = b.x * b.x + b.y * b.y + b.z * b.z + b.w * b.w;
  float dd = a.x * b.x + a.y * b.y + a.z * b.z + a.w * b.w;
#pragma unroll
  for (int d = 1; d < 64; d <<= 1) {
    si += __shfl_xor(si, d);
    sj += __shfl_xor(sj, d);
    dd += __shfl_xor(dd, d);
  }
  const float ni = fmaxf(sqrtf(si), EPS_), nj = fmaxf(sqrtf(sj), EPS_);
  const float ii = 1.0f / ni, ij = 1.0f / nj;
  ushort4 oi, oj;
  oi.x = f2bf_rne(a.x * ii); oi.y = f2bf_rne(a.y * ii);
  oi.z = f2bf_rne(a.z * ii); oi.w = f2bf_rne(a.w * ii);
  oj.x = f2bf_rne(b.x * ij); oj.y = f2bf_rne(b.y * ij);
  oj.z = f2bf_rne(b.z * ij); oj.w = f2bf_rne(b.w * ij);
  reinterpret_cast<ushort4*>(zn + (size_t)p * D_)[lane] = oi;
  reinterpret_cast<ushort4*>(zn + (size_t)(p + B_) * D_)[lane] = oj;
  if (lane == 0) {
    float v = dd / (ni * nj) * 2.0f;   // /T with T=0.5
    pos[p] = v;
    pos[p + B_] = v;
  }
}

// ---------------- flash LSE (fixed max = 2) ----------------
__global__ __launch_bounds__(256, 4) void k_flash(
    const ushort* __restrict__ zn, const int* __restrict__ labels,
    float* __restrict__ Spart) {
  __shared__ uint4 lds16[2 * BN * 32];   // 2 x 16KB tile buffers, swizzled
  __shared__ int labbuf[CPS];            // this split's column labels, 2KB
  const int tid = threadIdx.x;
  const int w = tid >> 6, lane = tid & 63;
  const int l15 = lane & 15, l4 = lane >> 4;
  const int c31 = lane & 31, lh = lane >> 5;

  // XCD-aware bijective swizzle: XCD x owns swz in [x*128,(x+1)*128) =
  // splits {2x,2x+1} x all 64 row-blocks (co-resident at 4 blocks/CU).
  const int bid = blockIdx.x;
  const int swz = (bid & 7) * 128 + (bid >> 3);
  const int rowblk = swz & 63, split = swz >> 6;
  const int arowb = rowblk * BM + w * 32;

  // A fragments: 32 rows x 256 K in registers for the whole block.
  bfrag_t a[2][KC];
#pragma unroll
  for (int mf = 0; mf < 2; ++mf) {
    const int ar = arowb + mf * 16 + l15;
#pragma unroll
    for (int kc = 0; kc < KC; ++kc)
      a[mf][kc] = *reinterpret_cast<const bfrag_t*>(
          zn + (size_t)ar * D_ + kc * 32 + l4 * 8);
  }

  // stage this split's labels into LDS once
  labbuf[tid]       = labels[(split * CPS + tid) & (B_ - 1)];
  labbuf[tid + 256] = labels[(split * CPS + tid + 256) & (B_ - 1)];

  int labR[2][4];
#pragma unroll
  for (int mf = 0; mf < 2; ++mf)
#pragma unroll
    for (int rg = 0; rg < 4; ++rg)
      labR[mf][rg] = labels[(arowb + mf * 16 + l4 * 4 + rg) & (B_ - 1)];

  float Srun[2][4];
#pragma unroll
  for (int mf = 0; mf < 2; ++mf)
#pragma unroll
    for (int rg = 0; rg < 4; ++rg) Srun[mf][rg] = 0.f;

  // hoisted per-lane addressing ------------------------------------------
  // ds_read byte offset: br*512 + ((p*4+l4)^(l15&7))*16 + nf*8192 + (kc>>1)*128
  // with br = nf*16+l15; nf and kc>>1 fold into immediates off 2 bases.
  const int offp0 = l15 * 512 + ((l4 ^ (l15 & 7)) << 4);
  const int offp1 = l15 * 512 + (((4 + l4) ^ (l15 & 7)) << 4);
  // stage: dest linear, src pre-swizzled. instr q covers dest rows w*8+q*2+lh.
  uint so[4];
#pragma unroll
  for (int q = 0; q < 4; ++q) {
    const int rw = w * 8 + q * 2 + lh;
    so[q] = rw * 32 + (c31 ^ (rw & 7));
  }
  const uint4* gsplit =
      reinterpret_cast<const uint4*>(zn) + (size_t)(split * CPS) * 32;

  auto stage = [&](int t) {
    const uint4* gt = gsplit + t * (BN * 32);
    uint4* db = lds16 + ((t & 1) * (BN * 32)) + w * 256;
#pragma unroll
    for (int q = 0; q < 4; ++q) cp16_lds(gt + so[q], db + q * 64);
  };

  stage(0);
  __syncthreads();   // buf0 + labbuf ready

#pragma unroll 2
  for (int ct = 0; ct < NT_; ++ct) {
    if (ct + 1 < NT_) stage(ct + 1);   // async refill of the idle buffer

    int labC[2];
#pragma unroll
    for (int nf = 0; nf < 2; ++nf)
      labC[nf] = labbuf[ct * BN + nf * 16 + l15];

    f32x4_t acc[2][2];
#pragma unroll
    for (int mf = 0; mf < 2; ++mf)
#pragma unroll
      for (int nf = 0; nf < 2; ++nf)
        acc[mf][nf] = (f32x4_t){0.f, 0.f, 0.f, 0.f};

    const char* lb = (const char*)lds16 + ((ct & 1) << 14);
#pragma unroll
    for (int kc = 0; kc < KC; ++kc) {
      const int kimm = (kc >> 1) << 7;
      const int po = (kc & 1) ? offp1 : offp0;
#pragma unroll
      for (int nf = 0; nf < 2; ++nf) {
        bfrag_t bf = *reinterpret_cast<const bfrag_t*>(
            lb + po + nf * 8192 + kimm);
        acc[0][nf] = __builtin_amdgcn_mfma_f32_16x16x32_bf16(a[0][kc], bf, acc[0][nf], 0, 0, 0);
        acc[1][nf] = __builtin_amdgcn_mfma_f32_16x16x32_bf16(a[1][kc], bf, acc[1][nf], 0, 0, 0);
      }
    }

    // fixed-max epilogue: S += exp(sim*2 - 2) masked by label equality
#pragma unroll
    for (int mf = 0; mf < 2; ++mf) {
#pragma unroll
      for (int rg = 0; rg < 4; ++rg) {
        const int rl = labR[mf][rg];
        float e0, e1;
        {
          float t0 = fmaf(acc[mf][0][rg], 2.0f * LOG2E, -2.0f * LOG2E);
          e0 = __builtin_amdgcn_exp2f(t0);
          e0 = (labC[0] != rl) ? e0 : 0.0f;
        }
        {
          float t1 = fmaf(acc[mf][1][rg], 2.0f * LOG2E, -2.0f * LOG2E);
          e1 = __builtin_amdgcn_exp2f(t1);
          e1 = (labC[1] != rl) ? e1 : 0.0f;
        }
        Srun[mf][rg] += e0 + e1;
      }
    }

    __syncthreads();   // frees buf[ct&1] for stage(ct+2); drains stage(ct+1)
  }

  // cross-lane (16 cols) sum, one write per row per split
#pragma unroll
  for (int mf = 0; mf < 2; ++mf) {
#pragma unroll
    for (int rg = 0; rg < 4; ++rg) {
      float s = Srun[mf][rg];
#pragma unroll
      for (int d = 1; d < 16; d <<= 1) s += __shfl_xor(s, d);
      if (l15 == 0)
        Spart[(size_t)split * N_ + arowb + mf * 16 + l4 * 4 + rg] = s;
    }
  }
}

// ---------------- finalize: single block, direct write ----------------
__global__ __launch_bounds__(1024) void k_finalize(
    const float* __restrict__ Spart, const float* __restrict__ pos,
    float* __restrict__ out) {
  __shared__ float red[16];
  const int tid = threadIdx.x;
  float c = 0.f;
#pragma unroll
  for (int k = 0; k < 8; ++k) {
    const int i = k * 1024 + tid;
    const float p = pos[i];
    float S = __builtin_amdgcn_exp2f(fmaf(p, LOG2E, -2.0f * LOG2E));  // exp(p-2)
#pragma unroll
    for (int s = 0; s < SPLITS; ++s) S += Spart[s * N_ + i];
    c += 2.0f + __logf(S) - p;   // lse_i - pos_i
  }
#pragma unroll
  for (int d = 1; d < 64; d <<= 1) c += __shfl_xor(c, d);
  if ((tid & 63) == 0) red[tid >> 6] = c;
  __syncthreads();
  if (tid == 0) {
    float t = 0.f;
#pragma unroll
    for (int q = 0; q < 16; ++q) t += red[q];
    out[0] = t * (1.0f / (float)N_);
  }
}

extern "C" void kernel_launch(void* const* d_in, const int* in_sizes, int n_in,
                              void* d_out, int out_size, void* d_ws, size_t ws_size,
                              hipStream_t stream) {
  (void)in_sizes; (void)n_in; (void)out_size; (void)ws_size;
  const float* zi = (const float*)d_in[0];
  const float* zj = (const float*)d_in[1];
  const int* labels = (const int*)d_in[2];
  char* ws = (char*)d_ws;
  ushort* zn   = (ushort*)(ws);                               // 4 MB
  float* pos   = (float*)(ws + 4u * 1024 * 1024);             // 32 KB
  float* Spart = (float*)(ws + 4u * 1024 * 1024 + 32 * 1024); // 512 KB
  float* out = (float*)d_out;

  k_prep<<<B_ / 4, 256, 0, stream>>>(zi, zj, zn, pos);
  k_flash<<<(N_ / BM) * SPLITS, 256, 0, stream>>>(zn, labels, Spart);
  k_finalize<<<1, 1024, 0, stream>>>(Spart, pos, out);
}